// Round 3
// baseline (270.571 us; speedup 1.0000x reference)
//
#include <hip/hip_runtime.h>

#define NRES 256
#define CIN  128
#define NH   4
#define DH   32

#define KST 32    // Ks row stride (u16)
#define VST 264   // Vt row stride (u16): pads 16-way store conflict to 2-way, 528 B = 16B-aligned
#define PST 40    // Pt row stride (u16): 80 B = 16B-aligned, banks 2-way
#define GST 136   // Gt row stride (u16): 272 B = 16B-aligned

typedef __attribute__((ext_vector_type(4))) float f32x4;
typedef __attribute__((ext_vector_type(8))) short bf16x8;

// packed RNE fp32->bf16 pair via v_perm (5 VALU ops / 2 values)
__device__ __forceinline__ unsigned pkbf(float a, float b) {
    unsigned ua = __builtin_bit_cast(unsigned, a);
    unsigned ub = __builtin_bit_cast(unsigned, b);
    ua += 0x7fffu + ((ua >> 16) & 1u);
    ub += 0x7fffu + ((ub >> 16) & 1u);
    return __builtin_amdgcn_perm(ub, ua, 0x07060302); // lo16=bf(a), hi16=bf(b)
}
__device__ __forceinline__ unsigned short f2bfu(float f) {
    unsigned u = __builtin_bit_cast(unsigned, f);
    return (unsigned short)((u + 0x7fffu + ((u >> 16) & 1u)) >> 16);
}
union bfr { unsigned u[4]; bf16x8 v; };
__device__ __forceinline__ bf16x8 ldcvt8(const float* __restrict__ p) {
    f32x4 a = *(const f32x4*)p; f32x4 b = *(const f32x4*)(p + 4);
    bfr r;
    r.u[0] = pkbf(a[0], a[1]); r.u[1] = pkbf(a[2], a[3]);
    r.u[2] = pkbf(b[0], b[1]); r.u[3] = pkbf(b[2], b[3]);
    return r.v;
}
__device__ __forceinline__ bf16x8 ldcvt8s(const float* __restrict__ p, float sc) {
    f32x4 a = *(const f32x4*)p; f32x4 b = *(const f32x4*)(p + 4);
    bfr r;
    r.u[0] = pkbf(a[0] * sc, a[1] * sc); r.u[1] = pkbf(a[2] * sc, a[3] * sc);
    r.u[2] = pkbf(b[0] * sc, b[1] * sc); r.u[3] = pkbf(b[2] * sc, b[3] * sc);
    return r.v;
}
#define MFMA(a, b, c) __builtin_amdgcn_mfma_f32_16x16x32_bf16((a), (b), (c), 0, 0, 0)

// ---------------------------------------------------------------------------
// Flash attention per (h, n). Fixed softmax max (m=8): scores = qk(<=0.3) +
// tri(<=~5) + mask{0,-1e9}; exp(s-8) never overflows, masked -> 0 exactly.
// Writes un-gated O to d_out as [n*256+q][h*32+d].
// ---------------------------------------------------------------------------
__global__ __launch_bounds__(256, 3) void attn_mfma(
    const float* __restrict__ q_x, const float* __restrict__ kv_x,
    const float* __restrict__ mask_bias, const float* __restrict__ tri_bias,
    const float* __restrict__ wq, const float* __restrict__ wk,
    const float* __restrict__ wv, float* __restrict__ o_out)
{
    const int h = blockIdx.x, n = blockIdx.y;
    const int t = threadIdx.x;
    const int lane = t & 63, w = t >> 6;
    const int mrow = lane & 15;
    const int grp  = lane >> 4;
    const int koff = grp * 8;
    const int rbase = grp * 4;
    const int q0 = w * 64;

    __shared__ unsigned short Ks[NRES * KST];    // 16384 B  [k][d]
    __shared__ unsigned short Vt[DH * VST];      // 16896 B  [d][k] padded
    __shared__ unsigned short Pt[4 * 32 * PST];  // 10240 B  per-wave transpose tile
    __shared__ float msk[NRES];                  //  1024 B
    // total 44.5 KB -> 3 blocks/CU

    if (t < 64) *(float4*)&msk[t * 4] = *(const float4*)(mask_bias + n * NRES + t * 4);

    const float* __restrict__ qxn = q_x  + (size_t)n * NRES * CIN;
    const float* __restrict__ kxn = kv_x + (size_t)n * NRES * CIN;
    const float* __restrict__ wqh = wq + h * DH * CIN;
    const float* __restrict__ wkh = wk + h * DH * CIN;
    const float* __restrict__ wvh = wv + h * DH * CIN;

    // ---------------- projections: Q(scaled), K, V ----------------
    f32x4 aq_[4][2], ak_[4][2], av_[4][2];
    const f32x4 zf = {0.f, 0.f, 0.f, 0.f};
    #pragma unroll
    for (int qt = 0; qt < 4; ++qt)
        #pragma unroll
        for (int dt = 0; dt < 2; ++dt) { aq_[qt][dt] = zf; ak_[qt][dt] = zf; av_[qt][dt] = zf; }

    const float qsc = 0.17677669529663687f; // 1/sqrt(32)
    #pragma unroll
    for (int ct = 0; ct < 4; ++ct) {
        const int c0 = ct * 32 + koff;
        bf16x8 bq0 = ldcvt8s(wqh + mrow * CIN + c0, qsc);
        bf16x8 bq1 = ldcvt8s(wqh + (16 + mrow) * CIN + c0, qsc);
        bf16x8 bk0 = ldcvt8(wkh + mrow * CIN + c0);
        bf16x8 bk1 = ldcvt8(wkh + (16 + mrow) * CIN + c0);
        bf16x8 bv0 = ldcvt8(wvh + mrow * CIN + c0);
        bf16x8 bv1 = ldcvt8(wvh + (16 + mrow) * CIN + c0);
        #pragma unroll
        for (int qt = 0; qt < 4; ++qt) {
            bf16x8 aX = ldcvt8(qxn + (q0 + qt * 16 + mrow) * CIN + c0);
            aq_[qt][0] = MFMA(aX, bq0, aq_[qt][0]);
            aq_[qt][1] = MFMA(aX, bq1, aq_[qt][1]);
            bf16x8 aK = ldcvt8(kxn + (q0 + qt * 16 + mrow) * CIN + c0);
            ak_[qt][0] = MFMA(aK, bk0, ak_[qt][0]);
            ak_[qt][1] = MFMA(aK, bk1, ak_[qt][1]);
            av_[qt][0] = MFMA(aK, bv0, av_[qt][0]);
            av_[qt][1] = MFMA(aK, bv1, av_[qt][1]);
        }
    }

    // scatter K,V (C-layout: row=grp*4+r, col=lane&15)
    #pragma unroll
    for (int qt = 0; qt < 4; ++qt)
        #pragma unroll
        for (int dt = 0; dt < 2; ++dt)
            #pragma unroll
            for (int r = 0; r < 4; ++r) {
                const int row = q0 + qt * 16 + rbase + r;
                const int d = dt * 16 + mrow;
                Ks[row * KST + d] = f2bfu(ak_[qt][dt][r]);
                Vt[d * VST + row] = f2bfu(av_[qt][dt][r]);
            }

    // Q transpose via per-wave Pt (C-layout -> A-frag), 2 halves of 32 rows
    unsigned short* __restrict__ pw = &Pt[w * 32 * PST];
    bf16x8 aq[4];
    #pragma unroll
    for (int h2 = 0; h2 < 2; ++h2) {
        #pragma unroll
        for (int j = 0; j < 2; ++j) {
            const int qt = h2 * 2 + j;
            #pragma unroll
            for (int dt = 0; dt < 2; ++dt)
                #pragma unroll
                for (int r = 0; r < 4; ++r)
                    pw[(j * 16 + rbase + r) * PST + dt * 16 + mrow] = f2bfu(aq_[qt][dt][r]);
        }
        asm volatile("s_waitcnt lgkmcnt(0)" ::: "memory");
        #pragma unroll
        for (int j = 0; j < 2; ++j)
            aq[h2 * 2 + j] = *(const bf16x8*)&pw[(j * 16 + mrow) * PST + koff];
        asm volatile("s_waitcnt lgkmcnt(0)" ::: "memory");
    }
    __syncthreads();

    // ---------------- flash loop, k-tiles of 32 ----------------
    f32x4 oa[4][2], ls4[4];
    #pragma unroll
    for (int qt = 0; qt < 4; ++qt) { oa[qt][0] = zf; oa[qt][1] = zf; ls4[qt] = zf; }

    const float* __restrict__ trih = tri_bias + (size_t)h * NRES * NRES;

    for (int kt = 0; kt < 8; ++kt) {
        const int kb = kt * 32;
        bf16x8 bk0 = *(const bf16x8*)&Ks[(kb + mrow) * KST + koff];
        bf16x8 bk1 = *(const bf16x8*)&Ks[(kb + 16 + mrow) * KST + koff];
        bf16x8 bv0 = *(const bf16x8*)&Vt[mrow * VST + kb + koff];
        bf16x8 bv1 = *(const bf16x8*)&Vt[(16 + mrow) * VST + kb + koff];
        const float mb0 = msk[kb + mrow] - 8.f;
        const float mb1 = msk[kb + 16 + mrow] - 8.f;

        #pragma unroll
        for (int h2 = 0; h2 < 2; ++h2) {
            float tr0[2][4], tr1[2][4];
            #pragma unroll
            for (int j = 0; j < 2; ++j) {     // prefetch tri for both q-tiles
                const int qt = h2 * 2 + j;
                const float* __restrict__ trow =
                    trih + (q0 + qt * 16 + rbase) * NRES + kb + mrow;
                #pragma unroll
                for (int r = 0; r < 4; ++r) {
                    tr0[j][r] = trow[r * NRES];
                    tr1[j][r] = trow[r * NRES + 16];
                }
            }
            #pragma unroll
            for (int j = 0; j < 2; ++j) {
                const int qt = h2 * 2 + j;
                f32x4 s0 = MFMA(aq[qt], bk0, zf);
                f32x4 s1 = MFMA(aq[qt], bk1, zf);
                #pragma unroll
                for (int r = 0; r < 4; ++r) {
                    s0[r] = __expf(s0[r] + tr0[j][r] + mb0);
                    s1[r] = __expf(s1[r] + tr1[j][r] + mb1);
                }
                ls4[qt] += s0 + s1;
                #pragma unroll
                for (int r = 0; r < 4; ++r) {
                    pw[(j * 16 + rbase + r) * PST + mrow]      = f2bfu(s0[r]);
                    pw[(j * 16 + rbase + r) * PST + 16 + mrow] = f2bfu(s1[r]);
                }
            }
            asm volatile("s_waitcnt lgkmcnt(0)" ::: "memory");
            #pragma unroll
            for (int j = 0; j < 2; ++j) {     // one drain serves 2 q-tiles
                const int qt = h2 * 2 + j;
                bf16x8 pa = *(const bf16x8*)&pw[(j * 16 + mrow) * PST + koff];
                oa[qt][0] = MFMA(pa, bv0, oa[qt][0]);
                oa[qt][1] = MFMA(pa, bv1, oa[qt][1]);
            }
        }
    }

    // ---------------- normalize + write O ----------------
    float* __restrict__ orow = o_out + (size_t)n * NRES * CIN + h * DH;
    #pragma unroll
    for (int qt = 0; qt < 4; ++qt) {
        f32x4 lv = ls4[qt];
        #pragma unroll
        for (int xm = 1; xm < 16; xm <<= 1) {
            lv[0] += __shfl_xor(lv[0], xm, 64);
            lv[1] += __shfl_xor(lv[1], xm, 64);
            lv[2] += __shfl_xor(lv[2], xm, 64);
            lv[3] += __shfl_xor(lv[3], xm, 64);
        }
        #pragma unroll
        for (int r = 0; r < 4; ++r) {
            const float inv = 1.f / lv[r];
            const int q = q0 + qt * 16 + rbase + r;
            orow[q * CIN + mrow]      = oa[qt][0][r] * inv;
            orow[q * CIN + 16 + mrow] = oa[qt][1][r] * inv;
        }
    }
}

// ---------------------------------------------------------------------------
// Fused gating + output projection, all-MFMA:
//   L = Xq*Wg^T (bf16 MFMA), g = sigmoid(L+bg), gated = O*g (O read fp32),
//   gated -> per-wave LDS transpose -> A-frag, out = gated*Wo^T + bo.
// In-place on d_out; each wave owns 32 rows (reads complete before writes
// via the acc2 data dependence). 128 rows/block.
// ---------------------------------------------------------------------------
__global__ __launch_bounds__(256, 4) void gate_out(
    const float* __restrict__ q_x, const float* __restrict__ wg,
    const float* __restrict__ bg, const float* __restrict__ wo,
    const float* __restrict__ bo, float* __restrict__ io)
{
    const int t = threadIdx.x;
    const int lane = t & 63, w = t >> 6;
    const int mrow = lane & 15, grp = lane >> 4;
    const int koff = grp * 8, rbase = grp * 4;
    const int r0 = blockIdx.x * 128 + w * 32;

    __shared__ unsigned short Gt[4 * 32 * GST];   // 34816 B, per-wave tiles
    unsigned short* __restrict__ gw = &Gt[w * 32 * GST];

    const f32x4 zf = {0.f, 0.f, 0.f, 0.f};
    f32x4 acc[2][8];
    #pragma unroll
    for (int at = 0; at < 2; ++at)
        #pragma unroll
        for (int nt = 0; nt < 8; ++nt) acc[at][nt] = zf;

    // phase A: logits = Xq * Wg^T
    #pragma unroll
    for (int ks = 0; ks < 4; ++ks) {
        const int c0 = ks * 32 + koff;
        bf16x8 ax0 = ldcvt8(q_x + (size_t)(r0 + mrow) * CIN + c0);
        bf16x8 ax1 = ldcvt8(q_x + (size_t)(r0 + 16 + mrow) * CIN + c0);
        #pragma unroll
        for (int nt = 0; nt < 8; ++nt) {
            bf16x8 bw = ldcvt8(wg + (nt * 16 + mrow) * CIN + c0);
            acc[0][nt] = MFMA(ax0, bw, acc[0][nt]);
            acc[1][nt] = MFMA(ax1, bw, acc[1][nt]);
        }
    }

    // sigmoid * O -> Gt (bf16, C-layout scatter)
    #pragma unroll
    for (int nt = 0; nt < 8; ++nt) {
        const float bge = bg[nt * 16 + mrow];
        #pragma unroll
        for (int at = 0; at < 2; ++at)
            #pragma unroll
            for (int r = 0; r < 4; ++r) {
                const int qg = r0 + at * 16 + rbase + r;
                const float ov = io[(size_t)qg * CIN + nt * 16 + mrow];
                const float g = 1.f / (1.f + __expf(-(acc[at][nt][r] + bge)));
                gw[(at * 16 + rbase + r) * GST + nt * 16 + mrow] = f2bfu(ov * g);
            }
    }
    asm volatile("s_waitcnt lgkmcnt(0)" ::: "memory");

    // phase B: out = gated * Wo^T + bo
    f32x4 acc2[2][8];
    #pragma unroll
    for (int at = 0; at < 2; ++at)
        #pragma unroll
        for (int nt = 0; nt < 8; ++nt) acc2[at][nt] = zf;

    #pragma unroll
    for (int ks = 0; ks < 4; ++ks) {
        const int e0 = ks * 32 + koff;
        bf16x8 ag0 = *(const bf16x8*)&gw[mrow * GST + e0];
        bf16x8 ag1 = *(const bf16x8*)&gw[(16 + mrow) * GST + e0];
        #pragma unroll
        for (int nt = 0; nt < 8; ++nt) {
            bf16x8 bw = ldcvt8(wo + (nt * 16 + mrow) * CIN + e0);
            acc2[0][nt] = MFMA(ag0, bw, acc2[0][nt]);
            acc2[1][nt] = MFMA(ag1, bw, acc2[1][nt]);
        }
    }

    #pragma unroll
    for (int nt = 0; nt < 8; ++nt) {
        const float boc = bo[nt * 16 + mrow];
        #pragma unroll
        for (int at = 0; at < 2; ++at)
            #pragma unroll
            for (int r = 0; r < 4; ++r)
                io[(size_t)(r0 + at * 16 + rbase + r) * CIN + nt * 16 + mrow] =
                    acc2[at][nt][r] + boc;
    }
}

extern "C" void kernel_launch(void* const* d_in, const int* in_sizes, int n_in,
                              void* d_out, int out_size, void* d_ws, size_t ws_size,
                              hipStream_t stream) {
    const float* q_x  = (const float*)d_in[0];
    const float* kv_x = (const float*)d_in[1];
    const float* mask = (const float*)d_in[2];
    const float* tri  = (const float*)d_in[3];
    const float* wq   = (const float*)d_in[4];
    const float* wk   = (const float*)d_in[5];
    const float* wv   = (const float*)d_in[6];
    const float* wg   = (const float*)d_in[7];
    const float* bg   = (const float*)d_in[8];
    const float* wo   = (const float*)d_in[9];
    const float* bo   = (const float*)d_in[10];
    float* out = (float*)d_out;

    attn_mfma<<<dim3(NH, NRES), 256, 0, stream>>>(q_x, kv_x, mask, tri, wq, wk, wv, out);
    gate_out<<<(NRES * NRES) / 128, 256, 0, stream>>>(q_x, wg, bg, wo, bo, out);
}

// Round 4
// 246.211 us; speedup vs baseline: 1.0989x; 1.0989x over previous
//
#include <hip/hip_runtime.h>

#define NRES 256
#define CIN  128
#define NH   4
#define DH   32

typedef __attribute__((ext_vector_type(4))) float f32x4;
typedef __attribute__((ext_vector_type(8))) short bf16x8;
typedef unsigned short u16;

// ---- ws layout (u16 units) ----
#define U_WQG 0                      // [256][128] bf16: rows 0-127 = wq*qsc, 128-255 = wg
#define U_WKV 32768                  // [256][128] bf16: rows 0-127 = wk, 128-255 = wv
#define U_WWO 65536                  // [128][128] bf16: wo[c][e]
#define U_QB  131072                 // [65536][128] bf16 scaled-Q
#define U_KB  (U_QB + 8388608)       // [65536][128] bf16 K
#define U_VT  (U_KB + 8388608)       // [256 n][128 d][256 k] bf16 V^T
#define U_GB  (U_VT + 8388608)       // [65536][128] bf16 sigmoid gate
#define WS_NEED ((size_t)(U_GB + 8388608) * 2)   // 67,371,008 B

// packed RNE fp32->bf16 pair via v_perm
__device__ __forceinline__ unsigned pkbf(float a, float b) {
    unsigned ua = __builtin_bit_cast(unsigned, a);
    unsigned ub = __builtin_bit_cast(unsigned, b);
    ua += 0x7fffu + ((ua >> 16) & 1u);
    ub += 0x7fffu + ((ub >> 16) & 1u);
    return __builtin_amdgcn_perm(ub, ua, 0x07060302);
}
__device__ __forceinline__ u16 f2bfu(float f) {
    unsigned u = __builtin_bit_cast(unsigned, f);
    return (u16)((u + 0x7fffu + ((u >> 16) & 1u)) >> 16);
}
__device__ __forceinline__ float bf2f(u16 v) {
    unsigned u = ((unsigned)v) << 16;
    return __builtin_bit_cast(float, u);
}
union bfr { unsigned u[4]; bf16x8 v; };
__device__ __forceinline__ bf16x8 ldcvt8(const float* __restrict__ p) {
    f32x4 a = *(const f32x4*)p; f32x4 b = *(const f32x4*)(p + 4);
    bfr r;
    r.u[0] = pkbf(a[0], a[1]); r.u[1] = pkbf(a[2], a[3]);
    r.u[2] = pkbf(b[0], b[1]); r.u[3] = pkbf(b[2], b[3]);
    return r.v;
}
__device__ __forceinline__ bf16x8 ldcvt8s(const float* __restrict__ p, float sc) {
    f32x4 a = *(const f32x4*)p; f32x4 b = *(const f32x4*)(p + 4);
    bfr r;
    r.u[0] = pkbf(a[0] * sc, a[1] * sc); r.u[1] = pkbf(a[2] * sc, a[3] * sc);
    r.u[2] = pkbf(b[0] * sc, b[1] * sc); r.u[3] = pkbf(b[2] * sc, b[3] * sc);
    return r.v;
}
#define MFMA(a, b, c) __builtin_amdgcn_mfma_f32_16x16x32_bf16((a), (b), (c), 0, 0, 0)

// ===========================================================================
// Kernel 1: weight pre-convert fp32 -> bf16 (scale folded into wq).
// 81920 elems, 8/thread -> 40 blocks x 256.
// ===========================================================================
__global__ void wconv(const float* __restrict__ wq, const float* __restrict__ wk,
                      const float* __restrict__ wv, const float* __restrict__ wg,
                      const float* __restrict__ wo, u16* __restrict__ ws)
{
    const int i0 = (blockIdx.x * 256 + threadIdx.x) * 8;
    const float qsc = 0.17677669529663687f;   // 1/sqrt(32)
    const float* src; u16* dst; float sc = 1.f;
    if (i0 < 32768) {
        const int e = i0 >> 7, c = i0 & 127;
        src = (e < 128 ? wq + e * CIN : wg + (e - 128) * CIN) + c;
        if (e < 128) sc = qsc;
        dst = ws + U_WQG + i0;
    } else if (i0 < 65536) {
        const int j = i0 - 32768, e = j >> 7, c = j & 127;
        src = (e < 128 ? wk + e * CIN : wv + (e - 128) * CIN) + c;
        dst = ws + U_WKV + j;
    } else {
        const int j = i0 - 65536;
        src = wo + j; dst = ws + U_WWO + j;
    }
    *(bf16x8*)dst = ldcvt8s(src, sc);
}

// ===========================================================================
// Kernel 2: projection GEMM. grid (1024, 2): y=0: q_x -> {Q(scaled), G=sigmoid},
// y=1: kv_x -> {K, V^T}. Block = 64 rows; wave = 16 rows x 256 outs, K=128.
// ===========================================================================
__global__ __launch_bounds__(256, 4) void proj(
    const float* __restrict__ q_x, const float* __restrict__ kv_x,
    const float* __restrict__ bg, u16* __restrict__ ws)
{
    const int t = threadIdx.x, lane = t & 63, w = t >> 6;
    const int mrow = lane & 15, grp = lane >> 4;
    const int koff = grp * 8, rbase = grp * 4;
    const int R0 = blockIdx.x * 64 + w * 16;
    const int ysel = blockIdx.y;
    const float* __restrict__ src = ysel ? kv_x : q_x;
    const u16* __restrict__ W = ws + (ysel ? U_WKV : U_WQG);

    const f32x4 zf = {0.f, 0.f, 0.f, 0.f};
    f32x4 acc[16];
    #pragma unroll
    for (int nt = 0; nt < 16; ++nt) acc[nt] = zf;

    #pragma unroll
    for (int ct = 0; ct < 4; ++ct) {
        const int c0 = ct * 32 + koff;
        bf16x8 aX = ldcvt8(src + (size_t)(R0 + mrow) * CIN + c0);
        #pragma unroll
        for (int nt = 0; nt < 16; ++nt) {
            bf16x8 bw = *(const bf16x8*)(W + (nt * 16 + mrow) * CIN + c0);
            acc[nt] = MFMA(aX, bw, acc[nt]);
        }
    }

    if (!ysel) {
        #pragma unroll
        for (int nt = 0; nt < 8; ++nt) {          // Q (already scaled via wq*qsc)
            const int e = nt * 16 + mrow;
            #pragma unroll
            for (int r = 0; r < 4; ++r)
                ws[U_QB + (size_t)(R0 + rbase + r) * CIN + e] = f2bfu(acc[nt][r]);
        }
        #pragma unroll
        for (int nt = 8; nt < 16; ++nt) {         // G = sigmoid(logit + bg)
            const int e = (nt - 8) * 16 + mrow;
            const float b = bg[e];
            #pragma unroll
            for (int r = 0; r < 4; ++r) {
                const float g = 1.f / (1.f + __expf(-(acc[nt][r] + b)));
                ws[U_GB + (size_t)(R0 + rbase + r) * CIN + e] = f2bfu(g);
            }
        }
    } else {
        #pragma unroll
        for (int nt = 0; nt < 8; ++nt) {          // K natural
            const int e = nt * 16 + mrow;
            #pragma unroll
            for (int r = 0; r < 4; ++r)
                ws[U_KB + (size_t)(R0 + rbase + r) * CIN + e] = f2bfu(acc[nt][r]);
        }
        const int n = R0 >> 8, k0 = (R0 & 255) + rbase;
        #pragma unroll
        for (int nt = 8; nt < 16; ++nt) {         // V transposed [n][d][k]
            const int dcol = (nt - 8) * 16 + mrow;
            uint2 v;
            v.x = pkbf(acc[nt][0], acc[nt][1]);
            v.y = pkbf(acc[nt][2], acc[nt][3]);
            *(uint2*)&ws[U_VT + ((size_t)n * 128 + dcol) * 256 + k0] = v;
        }
    }
}

// ===========================================================================
// Kernel 3: flash attention per (h, n). Frags loaded directly from ws (L2-hot).
// Fixed softmax max (m=8). Gating fused into epilogue. LDS = Pt + msk only.
// ===========================================================================
#define PST 40   // Pt row stride (u16): 80 B, 16B-aligned
__global__ __launch_bounds__(256, 4) void flash(
    const u16* __restrict__ ws, const float* __restrict__ mask_bias,
    const float* __restrict__ tri_bias, float* __restrict__ o_out)
{
    const int h = blockIdx.x, n = blockIdx.y;
    const int t = threadIdx.x, lane = t & 63, w = t >> 6;
    const int mrow = lane & 15, grp = lane >> 4;
    const int koff = grp * 8, rbase = grp * 4;
    const int q0 = w * 64;

    __shared__ u16 Pt[4 * 64 * PST];   // 20480 B, per-wave 64-row transpose tile
    __shared__ float msk[NRES];

    if (t < 64) *(float4*)&msk[t * 4] = *(const float4*)(mask_bias + n * NRES + t * 4);

    const u16* __restrict__ Qb = ws + U_QB + (size_t)n * NRES * CIN;
    const u16* __restrict__ Kb = ws + U_KB + (size_t)n * NRES * CIN;
    const u16* __restrict__ Vt = ws + U_VT + (size_t)n * 128 * 256;
    const u16* __restrict__ Gb = ws + U_GB + (size_t)n * NRES * CIN;
    const float* __restrict__ trih = tri_bias + (size_t)h * NRES * NRES;

    bf16x8 aq[4];
    #pragma unroll
    for (int qt = 0; qt < 4; ++qt)
        aq[qt] = *(const bf16x8*)(Qb + (size_t)(q0 + qt * 16 + mrow) * CIN + h * DH + koff);
    __syncthreads();   // msk visible

    const f32x4 zf = {0.f, 0.f, 0.f, 0.f};
    f32x4 oa[4][2], ls4[4];
    #pragma unroll
    for (int qt = 0; qt < 4; ++qt) { oa[qt][0] = zf; oa[qt][1] = zf; ls4[qt] = zf; }

    u16* __restrict__ pw = &Pt[w * 64 * PST];

    for (int kt = 0; kt < 8; ++kt) {
        const int kb = kt * 32;
        bf16x8 bk0 = *(const bf16x8*)(Kb + (size_t)(kb + mrow) * CIN + h * DH + koff);
        bf16x8 bk1 = *(const bf16x8*)(Kb + (size_t)(kb + 16 + mrow) * CIN + h * DH + koff);
        bf16x8 bv0 = *(const bf16x8*)(Vt + (size_t)(h * DH + mrow) * NRES + kb + koff);
        bf16x8 bv1 = *(const bf16x8*)(Vt + (size_t)(h * DH + 16 + mrow) * NRES + kb + koff);
        const float mb0 = msk[kb + mrow] - 8.f;
        const float mb1 = msk[kb + 16 + mrow] - 8.f;

        #pragma unroll
        for (int h2 = 0; h2 < 2; ++h2) {
            float tr0[2][4], tr1[2][4];
            #pragma unroll
            for (int j = 0; j < 2; ++j) {
                const int qt = h2 * 2 + j;
                const float* __restrict__ trow =
                    trih + (q0 + qt * 16 + rbase) * NRES + kb + mrow;
                #pragma unroll
                for (int r = 0; r < 4; ++r) {
                    tr0[j][r] = trow[r * NRES];
                    tr1[j][r] = trow[r * NRES + 16];
                }
            }
            #pragma unroll
            for (int j = 0; j < 2; ++j) {
                const int qt = h2 * 2 + j;
                f32x4 s0 = MFMA(aq[qt], bk0, zf);
                f32x4 s1 = MFMA(aq[qt], bk1, zf);
                #pragma unroll
                for (int r = 0; r < 4; ++r) {
                    s0[r] = __expf(s0[r] + tr0[j][r] + mb0);
                    s1[r] = __expf(s1[r] + tr1[j][r] + mb1);
                }
                ls4[qt] += s0 + s1;
                #pragma unroll
                for (int r = 0; r < 4; ++r) {
                    pw[(qt * 16 + rbase + r) * PST + mrow]      = f2bfu(s0[r]);
                    pw[(qt * 16 + rbase + r) * PST + 16 + mrow] = f2bfu(s1[r]);
                }
            }
        }
        asm volatile("s_waitcnt lgkmcnt(0)" ::: "memory");   // one drain per kt
        #pragma unroll
        for (int qt = 0; qt < 4; ++qt) {
            bf16x8 pa = *(const bf16x8*)&pw[(qt * 16 + mrow) * PST + koff];
            oa[qt][0] = MFMA(pa, bv0, oa[qt][0]);
            oa[qt][1] = MFMA(pa, bv1, oa[qt][1]);
        }
    }

    // epilogue: normalize + gate + store
    float* __restrict__ orow = o_out + (size_t)n * NRES * CIN + h * DH;
    #pragma unroll
    for (int qt = 0; qt < 4; ++qt) {
        f32x4 lv = ls4[qt];
        #pragma unroll
        for (int xm = 1; xm < 16; xm <<= 1) {
            lv[0] += __shfl_xor(lv[0], xm, 64);
            lv[1] += __shfl_xor(lv[1], xm, 64);
            lv[2] += __shfl_xor(lv[2], xm, 64);
            lv[3] += __shfl_xor(lv[3], xm, 64);
        }
        #pragma unroll
        for (int r = 0; r < 4; ++r) {
            const float inv = 1.f / lv[r];
            const int q = q0 + qt * 16 + rbase + r;
            const float g0 = bf2f(Gb[(size_t)q * CIN + h * DH + mrow]);
            const float g1 = bf2f(Gb[(size_t)q * CIN + h * DH + 16 + mrow]);
            orow[q * CIN + mrow]      = oa[qt][0][r] * inv * g0;
            orow[q * CIN + 16 + mrow] = oa[qt][1][r] * inv * g1;
        }
    }
}

// ===========================================================================
// Kernel 4: in-place output projection. out = gatedO * Wo^T + bo.
// Block = 128 rows, wave = 32 rows. All loads precede stores per wave.
// ===========================================================================
__global__ __launch_bounds__(256, 4) void gout(
    const u16* __restrict__ ws, const float* __restrict__ bo, float* io)
{
    const int t = threadIdx.x, lane = t & 63, w = t >> 6;
    const int mrow = lane & 15, grp = lane >> 4;
    const int koff = grp * 8, rbase = grp * 4;
    const int r0 = blockIdx.x * 128 + w * 32;
    const u16* __restrict__ Wo = ws + U_WWO;

    const f32x4 zf = {0.f, 0.f, 0.f, 0.f};
    f32x4 acc[2][8];
    #pragma unroll
    for (int at = 0; at < 2; ++at)
        #pragma unroll
        for (int nt = 0; nt < 8; ++nt) acc[at][nt] = zf;

    #pragma unroll
    for (int ks = 0; ks < 4; ++ks) {
        const int e0 = ks * 32 + koff;
        bf16x8 a0 = ldcvt8(io + (size_t)(r0 + mrow) * CIN + e0);
        bf16x8 a1 = ldcvt8(io + (size_t)(r0 + 16 + mrow) * CIN + e0);
        #pragma unroll
        for (int nt = 0; nt < 8; ++nt) {
            bf16x8 bw = *(const bf16x8*)(Wo + (nt * 16 + mrow) * CIN + e0);
            acc[0][nt] = MFMA(a0, bw, acc[0][nt]);
            acc[1][nt] = MFMA(a1, bw, acc[1][nt]);
        }
    }

    #pragma unroll
    for (int nt = 0; nt < 8; ++nt) {
        const float bc = bo[nt * 16 + mrow];
        #pragma unroll
        for (int at = 0; at < 2; ++at)
            #pragma unroll
            for (int r = 0; r < 4; ++r)
                io[(size_t)(r0 + at * 16 + rbase + r) * CIN + nt * 16 + mrow] =
                    acc[at][nt][r] + bc;
    }
}

// ===========================================================================
// Fallback path (R3 kernels, proven correct) for small ws_size.
// ===========================================================================
#define KST 32
#define VST 264
#define GST 136

__global__ __launch_bounds__(256, 3) void attn_fb(
    const float* __restrict__ q_x, const float* __restrict__ kv_x,
    const float* __restrict__ mask_bias, const float* __restrict__ tri_bias,
    const float* __restrict__ wq, const float* __restrict__ wk,
    const float* __restrict__ wv, float* __restrict__ o_out)
{
    const int h = blockIdx.x, n = blockIdx.y;
    const int t = threadIdx.x;
    const int lane = t & 63, w = t >> 6;
    const int mrow = lane & 15;
    const int grp  = lane >> 4;
    const int koff = grp * 8;
    const int rbase = grp * 4;
    const int q0 = w * 64;

    __shared__ u16 Ks[NRES * KST];
    __shared__ u16 Vt[DH * VST];
    __shared__ u16 Ptb[4 * 32 * PST];
    __shared__ float msk[NRES];

    if (t < 64) *(float4*)&msk[t * 4] = *(const float4*)(mask_bias + n * NRES + t * 4);

    const float* __restrict__ qxn = q_x  + (size_t)n * NRES * CIN;
    const float* __restrict__ kxn = kv_x + (size_t)n * NRES * CIN;
    const float* __restrict__ wqh = wq + h * DH * CIN;
    const float* __restrict__ wkh = wk + h * DH * CIN;
    const float* __restrict__ wvh = wv + h * DH * CIN;

    f32x4 aq_[4][2], ak_[4][2], av_[4][2];
    const f32x4 zf = {0.f, 0.f, 0.f, 0.f};
    #pragma unroll
    for (int qt = 0; qt < 4; ++qt)
        #pragma unroll
        for (int dt = 0; dt < 2; ++dt) { aq_[qt][dt] = zf; ak_[qt][dt] = zf; av_[qt][dt] = zf; }

    const float qsc = 0.17677669529663687f;
    #pragma unroll
    for (int ct = 0; ct < 4; ++ct) {
        const int c0 = ct * 32 + koff;
        bf16x8 bq0 = ldcvt8s(wqh + mrow * CIN + c0, qsc);
        bf16x8 bq1 = ldcvt8s(wqh + (16 + mrow) * CIN + c0, qsc);
        bf16x8 bk0 = ldcvt8(wkh + mrow * CIN + c0);
        bf16x8 bk1 = ldcvt8(wkh + (16 + mrow) * CIN + c0);
        bf16x8 bv0 = ldcvt8(wvh + mrow * CIN + c0);
        bf16x8 bv1 = ldcvt8(wvh + (16 + mrow) * CIN + c0);
        #pragma unroll
        for (int qt = 0; qt < 4; ++qt) {
            bf16x8 aX = ldcvt8(qxn + (q0 + qt * 16 + mrow) * CIN + c0);
            aq_[qt][0] = MFMA(aX, bq0, aq_[qt][0]);
            aq_[qt][1] = MFMA(aX, bq1, aq_[qt][1]);
            bf16x8 aK = ldcvt8(kxn + (q0 + qt * 16 + mrow) * CIN + c0);
            ak_[qt][0] = MFMA(aK, bk0, ak_[qt][0]);
            ak_[qt][1] = MFMA(aK, bk1, ak_[qt][1]);
            av_[qt][0] = MFMA(aK, bv0, av_[qt][0]);
            av_[qt][1] = MFMA(aK, bv1, av_[qt][1]);
        }
    }

    #pragma unroll
    for (int qt = 0; qt < 4; ++qt)
        #pragma unroll
        for (int dt = 0; dt < 2; ++dt)
            #pragma unroll
            for (int r = 0; r < 4; ++r) {
                const int row = q0 + qt * 16 + rbase + r;
                const int d = dt * 16 + mrow;
                Ks[row * KST + d] = f2bfu(ak_[qt][dt][r]);
                Vt[d * VST + row] = f2bfu(av_[qt][dt][r]);
            }

    u16* __restrict__ pw = &Ptb[w * 32 * PST];
    bf16x8 aq[4];
    #pragma unroll
    for (int h2 = 0; h2 < 2; ++h2) {
        #pragma unroll
        for (int j = 0; j < 2; ++j) {
            const int qt = h2 * 2 + j;
            #pragma unroll
            for (int dt = 0; dt < 2; ++dt)
                #pragma unroll
                for (int r = 0; r < 4; ++r)
                    pw[(j * 16 + rbase + r) * PST + dt * 16 + mrow] = f2bfu(aq_[qt][dt][r]);
        }
        asm volatile("s_waitcnt lgkmcnt(0)" ::: "memory");
        #pragma unroll
        for (int j = 0; j < 2; ++j)
            aq[h2 * 2 + j] = *(const bf16x8*)&pw[(j * 16 + mrow) * PST + koff];
        asm volatile("s_waitcnt lgkmcnt(0)" ::: "memory");
    }
    __syncthreads();

    f32x4 oa[4][2], ls4[4];
    #pragma unroll
    for (int qt = 0; qt < 4; ++qt) { oa[qt][0] = zf; oa[qt][1] = zf; ls4[qt] = zf; }

    const float* __restrict__ trih = tri_bias + (size_t)h * NRES * NRES;

    for (int kt = 0; kt < 8; ++kt) {
        const int kb = kt * 32;
        bf16x8 bk0 = *(const bf16x8*)&Ks[(kb + mrow) * KST + koff];
        bf16x8 bk1 = *(const bf16x8*)&Ks[(kb + 16 + mrow) * KST + koff];
        bf16x8 bv0 = *(const bf16x8*)&Vt[mrow * VST + kb + koff];
        bf16x8 bv1 = *(const bf16x8*)&Vt[(16 + mrow) * VST + kb + koff];
        const float mb0 = msk[kb + mrow] - 8.f;
        const float mb1 = msk[kb + 16 + mrow] - 8.f;

        #pragma unroll
        for (int h2 = 0; h2 < 2; ++h2) {
            float tr0[2][4], tr1[2][4];
            #pragma unroll
            for (int j = 0; j < 2; ++j) {
                const int qt = h2 * 2 + j;
                const float* __restrict__ trow =
                    trih + (q0 + qt * 16 + rbase) * NRES + kb + mrow;
                #pragma unroll
                for (int r = 0; r < 4; ++r) {
                    tr0[j][r] = trow[r * NRES];
                    tr1[j][r] = trow[r * NRES + 16];
                }
            }
            #pragma unroll
            for (int j = 0; j < 2; ++j) {
                const int qt = h2 * 2 + j;
                f32x4 s0 = MFMA(aq[qt], bk0, zf);
                f32x4 s1 = MFMA(aq[qt], bk1, zf);
                #pragma unroll
                for (int r = 0; r < 4; ++r) {
                    s0[r] = __expf(s0[r] + tr0[j][r] + mb0);
                    s1[r] = __expf(s1[r] + tr1[j][r] + mb1);
                }
                ls4[qt] += s0 + s1;
                #pragma unroll
                for (int r = 0; r < 4; ++r) {
                    pw[(j * 16 + rbase + r) * PST + mrow]      = f2bfu(s0[r]);
                    pw[(j * 16 + rbase + r) * PST + 16 + mrow] = f2bfu(s1[r]);
                }
            }
            asm volatile("s_waitcnt lgkmcnt(0)" ::: "memory");
            #pragma unroll
            for (int j = 0; j < 2; ++j) {
                const int qt = h2 * 2 + j;
                bf16x8 pa = *(const bf16x8*)&pw[(j * 16 + mrow) * PST + koff];
                oa[qt][0] = MFMA(pa, bv0, oa[qt][0]);
                oa[qt][1] = MFMA(pa, bv1, oa[qt][1]);
            }
        }
    }

    float* __restrict__ orow = o_out + (size_t)n * NRES * CIN + h * DH;
    #pragma unroll
    for (int qt = 0; qt < 4; ++qt) {
        f32x4 lv = ls4[qt];
        #pragma unroll
        for (int xm = 1; xm < 16; xm <<= 1) {
            lv[0] += __shfl_xor(lv[0], xm, 64);
            lv[1] += __shfl_xor(lv[1], xm, 64);
            lv[2] += __shfl_xor(lv[2], xm, 64);
            lv[3] += __shfl_xor(lv[3], xm, 64);
        }
        #pragma unroll
        for (int r = 0; r < 4; ++r) {
            const float inv = 1.f / lv[r];
            const int q = q0 + qt * 16 + rbase + r;
            orow[q * CIN + mrow]      = oa[qt][0][r] * inv;
            orow[q * CIN + 16 + mrow] = oa[qt][1][r] * inv;
        }
    }
}

__global__ __launch_bounds__(256, 4) void gate_fb(
    const float* __restrict__ q_x, const float* __restrict__ wg,
    const float* __restrict__ bg, const float* __restrict__ wo,
    const float* __restrict__ bo, float* io)
{
    const int t = threadIdx.x;
    const int lane = t & 63, w = t >> 6;
    const int mrow = lane & 15, grp = lane >> 4;
    const int koff = grp * 8, rbase = grp * 4;
    const int r0 = blockIdx.x * 128 + w * 32;

    __shared__ u16 Gt[4 * 32 * GST];
    u16* __restrict__ gw = &Gt[w * 32 * GST];

    const f32x4 zf = {0.f, 0.f, 0.f, 0.f};
    f32x4 acc[2][8];
    #pragma unroll
    for (int at = 0; at < 2; ++at)
        #pragma unroll
        for (int nt = 0; nt < 8; ++nt) acc[at][nt] = zf;

    #pragma unroll
    for (int ks = 0; ks < 4; ++ks) {
        const int c0 = ks * 32 + koff;
        bf16x8 ax0 = ldcvt8(q_x + (size_t)(r0 + mrow) * CIN + c0);
        bf16x8 ax1 = ldcvt8(q_x + (size_t)(r0 + 16 + mrow) * CIN + c0);
        #pragma unroll
        for (int nt = 0; nt < 8; ++nt) {
            bf16x8 bw = ldcvt8(wg + (nt * 16 + mrow) * CIN + c0);
            acc[0][nt] = MFMA(ax0, bw, acc[0][nt]);
            acc[1][nt] = MFMA(ax1, bw, acc[1][nt]);
        }
    }

    #pragma unroll
    for (int nt = 0; nt < 8; ++nt) {
        const float bge = bg[nt * 16 + mrow];
        #pragma unroll
        for (int at = 0; at < 2; ++at)
            #pragma unroll
            for (int r = 0; r < 4; ++r) {
                const int qg = r0 + at * 16 + rbase + r;
                const float ov = io[(size_t)qg * CIN + nt * 16 + mrow];
                const float g = 1.f / (1.f + __expf(-(acc[at][nt][r] + bge)));
                gw[(at * 16 + rbase + r) * GST + nt * 16 + mrow] = f2bfu(ov * g);
            }
    }
    asm volatile("s_waitcnt lgkmcnt(0)" ::: "memory");

    f32x4 acc2[2][8];
    #pragma unroll
    for (int at = 0; at < 2; ++at)
        #pragma unroll
        for (int nt = 0; nt < 8; ++nt) acc2[at][nt] = zf;

    #pragma unroll
    for (int ks = 0; ks < 4; ++ks) {
        const int e0 = ks * 32 + koff;
        bf16x8 ag0 = *(const bf16x8*)&gw[mrow * GST + e0];
        bf16x8 ag1 = *(const bf16x8*)&gw[(16 + mrow) * GST + e0];
        #pragma unroll
        for (int nt = 0; nt < 8; ++nt) {
            bf16x8 bw = ldcvt8(wo + (nt * 16 + mrow) * CIN + e0);
            acc2[0][nt] = MFMA(ag0, bw, acc2[0][nt]);
            acc2[1][nt] = MFMA(ag1, bw, acc2[1][nt]);
        }
    }

    #pragma unroll
    for (int nt = 0; nt < 8; ++nt) {
        const float boc = bo[nt * 16 + mrow];
        #pragma unroll
        for (int at = 0; at < 2; ++at)
            #pragma unroll
            for (int r = 0; r < 4; ++r)
                io[(size_t)(r0 + at * 16 + rbase + r) * CIN + nt * 16 + mrow] =
                    acc2[at][nt][r] + boc;
    }
}

extern "C" void kernel_launch(void* const* d_in, const int* in_sizes, int n_in,
                              void* d_out, int out_size, void* d_ws, size_t ws_size,
                              hipStream_t stream) {
    const float* q_x  = (const float*)d_in[0];
    const float* kv_x = (const float*)d_in[1];
    const float* mask = (const float*)d_in[2];
    const float* tri  = (const float*)d_in[3];
    const float* wq   = (const float*)d_in[4];
    const float* wk   = (const float*)d_in[5];
    const float* wv   = (const float*)d_in[6];
    const float* wg   = (const float*)d_in[7];
    const float* bg   = (const float*)d_in[8];
    const float* wo   = (const float*)d_in[9];
    const float* bo   = (const float*)d_in[10];
    float* out = (float*)d_out;

    if (ws_size >= WS_NEED) {
        u16* ws16 = (u16*)d_ws;
        wconv<<<40, 256, 0, stream>>>(wq, wk, wv, wg, wo, ws16);
        proj<<<dim3(1024, 2), 256, 0, stream>>>(q_x, kv_x, bg, ws16);
        flash<<<dim3(NH, NRES), 256, 0, stream>>>(ws16, mask, tri, out);
        gout<<<512, 256, 0, stream>>>(ws16, bo, out);
    } else {
        attn_fb<<<dim3(NH, NRES), 256, 0, stream>>>(q_x, kv_x, mask, tri, wq, wk, wv, out);
        gate_fb<<<(NRES * NRES) / 128, 256, 0, stream>>>(q_x, wg, bg, wo, bo, out);
    }
}